// Round 2
// baseline (281.104 us; speedup 1.0000x reference)
//
#include <hip/hip_runtime.h>
#include <hip/hip_bf16.h>
#include <stdint.h>
#include <math.h>

#define B_ 2
#define T_ 2048
#define D_ 1024
#define H_ 16
#define HD_ 64
#define M_ 4096   // B_*T_

using bf16 = __hip_bfloat16;
using short8 = __attribute__((ext_vector_type(8))) short;
using f32x4 = __attribute__((ext_vector_type(4))) float;

// async global->LDS, 16B per lane. LDS dest must be wave-uniform base + lane*16.
__device__ __forceinline__ void async16(const void* g, void* l) {
  __builtin_amdgcn_global_load_lds((const __attribute__((address_space(1))) void*)g,
                                   (__attribute__((address_space(3))) void*)l, 16, 0, 0);
}

// ---------------- cast x: fp32 [4096*1024] -> bf16 ----------------
__global__ __launch_bounds__(256) void cast_x(const float* __restrict__ x, bf16* __restrict__ xb) {
  const int i = (blockIdx.x * 256 + threadIdx.x) * 8;   // 8 elements/thread
  float4 a = *(const float4*)(x + i);
  float4 b = *(const float4*)(x + i + 4);
  bf16 o[8] = { __float2bfloat16(a.x), __float2bfloat16(a.y), __float2bfloat16(a.z), __float2bfloat16(a.w),
                __float2bfloat16(b.x), __float2bfloat16(b.y), __float2bfloat16(b.z), __float2bfloat16(b.w) };
  *(uint4*)(xb + i) = *(const uint4*)o;
}

// ---------------- weight transpose: W[k][n] fp32 -> Wt[n][k] bf16, 4 matrices ----------------
__global__ __launch_bounds__(256) void transpose4(const float* __restrict__ wq, const float* __restrict__ wk,
                                                  const float* __restrict__ wv, const float* __restrict__ wo,
                                                  bf16* __restrict__ wt) {
  __shared__ float tile[32][33];
  const int which = blockIdx.z;
  const float* src = which==0?wq:which==1?wk:which==2?wv:wo;
  bf16* dst = wt + ((size_t)which << 20);
  const int tx = threadIdx.x, ty = threadIdx.y;   // (32,8)
  const int row0 = blockIdx.y*32;
  const int col  = blockIdx.x*32 + tx;
  #pragma unroll
  for (int j=ty; j<32; j+=8) tile[j][tx] = src[(size_t)(row0+j)*D_ + col];
  __syncthreads();
  const int ocol  = row0 + tx;          // dst col = src row
  const int orow0 = blockIdx.x*32;      // dst row = src col
  #pragma unroll
  for (int j=ty; j<32; j+=8) dst[(size_t)(orow0+j)*D_ + ocol] = __float2bfloat16(tile[tx][j]);
}

// ---------------- fused QKV GEMM: [4096,1024] @ [1024,3072] + bias ----------------
// out layouts: Q,K = [b][h][t][hd]; V = [b][h][hd][t] (pre-transposed for attention)
__global__ __launch_bounds__(256,1) void qkv_gemm(const bf16* __restrict__ X, const bf16* __restrict__ Wt,
                                                  const float* __restrict__ bq, const float* __restrict__ bk,
                                                  const float* __restrict__ bv,
                                                  bf16* __restrict__ Qb, bf16* __restrict__ Kb, bf16* __restrict__ Vb) {
  __shared__ bf16 As[128*32];
  __shared__ bf16 Bs[128*32];
  const int tid = threadIdx.x;
  const int lane = tid & 63, wave = tid >> 6;
  const int quad = lane >> 4, l16 = lane & 15;
  const int wm = (wave >> 1) * 64, wn = (wave & 1) * 64;
  const int m0  = blockIdx.x * 128;
  const int nt0 = blockIdx.y * 128;          // 0..3071
  const int which = nt0 >> 10;               // 0=Q 1=K 2=V
  const int n0 = nt0 & 1023;
  const bf16* W = Wt + ((size_t)which << 20);
  const float* bias = which==0 ? bq : (which==1 ? bk : bv);
  bf16* out = which==0 ? Qb : (which==1 ? Kb : Vb);

  f32x4 acc[4][4];
  #pragma unroll
  for (int i=0;i<4;i++)
    #pragma unroll
    for (int j=0;j<4;j++) acc[i][j] = (f32x4){0.f,0.f,0.f,0.f};

  for (int k0 = 0; k0 < 1024; k0 += 32) {
    __syncthreads();
    #pragma unroll
    for (int it=0; it<2; ++it) {
      int id = tid + it*256;               // 0..511
      int row = id >> 2, seg = id & 3;
      async16(X + (size_t)(m0+row)*1024 + k0 + seg*8, (char*)As + id*16);
      async16(W + (size_t)(n0+row)*1024 + k0 + seg*8, (char*)Bs + id*16);
    }
    __syncthreads();   // drains vmcnt before barrier -> LDS valid
    short8 af[4], bfv[4];
    #pragma unroll
    for (int i=0;i<4;i++) af[i]  = *(const short8*)(As + (wm + i*16 + l16)*32 + quad*8);
    #pragma unroll
    for (int j=0;j<4;j++) bfv[j] = *(const short8*)(Bs + (wn + j*16 + l16)*32 + quad*8);
    #pragma unroll
    for (int i=0;i<4;i++)
      #pragma unroll
      for (int j=0;j<4;j++)
        acc[i][j] = __builtin_amdgcn_mfma_f32_16x16x32_bf16(af[i], bfv[j], acc[i][j], 0, 0, 0);
  }

  #pragma unroll
  for (int i=0;i<4;i++) {
    #pragma unroll
    for (int j=0;j<4;j++) {
      const int n = n0 + wn + j*16 + l16;
      const float bvv = bias[n];
      const int h = n >> 6, hd = n & 63;
      #pragma unroll
      for (int r=0;r<4;r++) {
        const int m = m0 + wm + i*16 + quad*4 + r;
        const int b = m >> 11, t = m & 2047;
        const float v = acc[i][j][r] + bvv;
        size_t idx;
        if (which == 2) idx = (((size_t)b*H_ + h)*HD_ + hd)*T_ + t;   // V transposed
        else            idx = (((size_t)b*H_ + h)*T_ + t)*HD_ + hd;
        out[idx] = __float2bfloat16(v);
      }
    }
  }
}

// ---------------- flash attention: per block one (b,h) x 64 q-rows ----------------
__global__ __launch_bounds__(256,1) void attn_kernel(const bf16* __restrict__ Qg, const bf16* __restrict__ Kg,
                                                     const bf16* __restrict__ Vg, bf16* __restrict__ Og) {
  __shared__ bf16 Qs[64*72];        // q-rows x hd, padded stride 72
  __shared__ bf16 Ks[128*72];       // keys  x hd, padded stride 72
  __shared__ bf16 Vts[64*136];      // hd x keys, padded stride 136
  __shared__ bf16 Ps[4][16*136];    // per-wave P strip, padded stride 136

  const int tid = threadIdx.x;
  const int lane = tid & 63, wave = tid >> 6;
  const int quad = lane >> 4, l16 = lane & 15;
  const int bh = blockIdx.y;              // 0..31
  const int q0 = blockIdx.x * 64;

  const bf16* Qp = Qg + (size_t)bh*T_*HD_;
  const bf16* Kp = Kg + (size_t)bh*T_*HD_;
  const bf16* Vp = Vg + (size_t)bh*HD_*T_;

  // stage Q tile [64][64] -> Qs[64][72]
  #pragma unroll
  for (int it=0; it<2; ++it) {
    int id = tid + it*256;               // 0..511
    int row = id >> 3, seg = id & 7;
    *(uint4*)(&Qs[row*72 + seg*8]) = *(const uint4*)(Qp + (size_t)(q0+row)*HD_ + seg*8);
  }
  __syncthreads();

  short8 qf[2];
  #pragma unroll
  for (int ks=0; ks<2; ++ks)
    qf[ks] = *(const short8*)(&Qs[(wave*16 + l16)*72 + ks*32 + quad*8]);

  f32x4 o_acc[4];
  #pragma unroll
  for (int jv=0;jv<4;jv++) o_acc[jv] = (f32x4){0.f,0.f,0.f,0.f};
  float m_run[4], l_run[4];
  #pragma unroll
  for (int r=0;r<4;r++){ m_run[r] = -1e30f; l_run[r] = 0.f; }

  const float SCL = 0.125f * 1.44269504088896340736f;   // 1/sqrt(64) * log2(e)
  bf16* Pw = &Ps[wave][0];

  for (int kt=0; kt<T_/128; ++kt) {
    __syncthreads();
    // stage K tile [128][64] -> Ks[128][72]
    #pragma unroll
    for (int it=0; it<4; ++it) {
      int id = tid + it*256;             // 0..1023
      int row = id >> 3, seg = id & 7;
      *(uint4*)(&Ks[row*72 + seg*8]) = *(const uint4*)(Kp + (size_t)(kt*128+row)*HD_ + seg*8);
    }
    // stage V tile [64][128] -> Vts[64][136]
    #pragma unroll
    for (int it=0; it<4; ++it) {
      int id = tid + it*256;             // 0..1023
      int row = id >> 4, seg = id & 15;
      *(uint4*)(&Vts[row*136 + seg*8]) = *(const uint4*)(Vp + (size_t)row*T_ + kt*128 + seg*8);
    }
    __syncthreads();

    // S strip 16 x 128 = Q(16x64) @ K^T
    f32x4 s_acc[8];
    #pragma unroll
    for (int j=0;j<8;j++) s_acc[j] = (f32x4){0.f,0.f,0.f,0.f};
    #pragma unroll
    for (int ks=0; ks<2; ++ks) {
      #pragma unroll
      for (int j=0;j<8;j++) {
        short8 kf = *(const short8*)(&Ks[(j*16 + l16)*72 + ks*32 + quad*8]);
        s_acc[j] = __builtin_amdgcn_mfma_f32_16x16x32_bf16(qf[ks], kf, s_acc[j], 0, 0, 0);
      }
    }

    // online softmax (log2 domain), write P strip to wave-private LDS
    #pragma unroll
    for (int r=0;r<4;r++) {
      float mx = -1e30f;
      #pragma unroll
      for (int j=0;j<8;j++) mx = fmaxf(mx, s_acc[j][r]);
      mx *= SCL;
      #pragma unroll
      for (int off=1; off<16; off<<=1) mx = fmaxf(mx, __shfl_xor(mx, off));
      const float mN = fmaxf(m_run[r], mx);
      const float alpha = exp2f(m_run[r] - mN);
      m_run[r] = mN;
      float sum = 0.f;
      #pragma unroll
      for (int j=0;j<8;j++) {
        float pv = exp2f(s_acc[j][r]*SCL - mN);
        sum += pv;
        Pw[(quad*4+r)*136 + j*16 + l16] = __float2bfloat16(pv);
      }
      #pragma unroll
      for (int off=1; off<16; off<<=1) sum += __shfl_xor(sum, off);
      l_run[r] = l_run[r]*alpha + sum;
      #pragma unroll
      for (int jv=0;jv<4;jv++) o_acc[jv][r] *= alpha;
    }

    // O strip += P(16x128) @ V(128x64)
    #pragma unroll
    for (int ks=0; ks<4; ++ks) {
      short8 pf = *(const short8*)(&Pw[l16*136 + ks*32 + quad*8]);
      #pragma unroll
      for (int jv=0;jv<4;jv++) {
        short8 vf = *(const short8*)(&Vts[(jv*16 + l16)*136 + ks*32 + quad*8]);
        o_acc[jv] = __builtin_amdgcn_mfma_f32_16x16x32_bf16(pf, vf, o_acc[jv], 0, 0, 0);
      }
    }
  }

  // epilogue: normalize and write O as [b][t][h*64+hd]
  const int b = bh >> 4, h = bh & 15;
  #pragma unroll
  for (int jv=0;jv<4;jv++) {
    #pragma unroll
    for (int r=0;r<4;r++) {
      const int row = q0 + wave*16 + quad*4 + r;
      const float ov = o_acc[jv][r] / l_run[r];
      Og[((size_t)b*T_ + row)*D_ + h*HD_ + jv*16 + l16] = __float2bfloat16(ov);
    }
  }
}

// ---------------- output projection + bias + residual(fp32) -> fp32 tmp ----------------
__global__ __launch_bounds__(256,1) void proj_gemm(const bf16* __restrict__ A, const bf16* __restrict__ Wt,
                                                   const float* __restrict__ bo, const float* __restrict__ Xres,
                                                   float* __restrict__ tmp) {
  __shared__ bf16 As[128*32];
  __shared__ bf16 Bs[128*32];
  const int tid = threadIdx.x;
  const int lane = tid & 63, wave = tid >> 6;
  const int quad = lane >> 4, l16 = lane & 15;
  const int wm = (wave >> 1) * 64, wn = (wave & 1) * 64;
  const int m0 = blockIdx.x * 128;
  const int n0 = blockIdx.y * 128;

  f32x4 acc[4][4];
  #pragma unroll
  for (int i=0;i<4;i++)
    #pragma unroll
    for (int j=0;j<4;j++) acc[i][j] = (f32x4){0.f,0.f,0.f,0.f};

  for (int k0 = 0; k0 < 1024; k0 += 32) {
    __syncthreads();
    #pragma unroll
    for (int it=0; it<2; ++it) {
      int id = tid + it*256;
      int row = id >> 2, seg = id & 3;
      async16(A  + (size_t)(m0+row)*1024 + k0 + seg*8, (char*)As + id*16);
      async16(Wt + (size_t)(n0+row)*1024 + k0 + seg*8, (char*)Bs + id*16);
    }
    __syncthreads();
    short8 af[4], bfv[4];
    #pragma unroll
    for (int i=0;i<4;i++) af[i]  = *(const short8*)(As + (wm + i*16 + l16)*32 + quad*8);
    #pragma unroll
    for (int j=0;j<4;j++) bfv[j] = *(const short8*)(Bs + (wn + j*16 + l16)*32 + quad*8);
    #pragma unroll
    for (int i=0;i<4;i++)
      #pragma unroll
      for (int j=0;j<4;j++)
        acc[i][j] = __builtin_amdgcn_mfma_f32_16x16x32_bf16(af[i], bfv[j], acc[i][j], 0, 0, 0);
  }

  #pragma unroll
  for (int i=0;i<4;i++) {
    #pragma unroll
    for (int j=0;j<4;j++) {
      const int n = n0 + wn + j*16 + l16;
      const float bvv = bo[n];
      #pragma unroll
      for (int r=0;r<4;r++) {
        const int m = m0 + wm + i*16 + quad*4 + r;
        tmp[(size_t)m*1024 + n] = acc[i][j][r] + bvv + Xres[(size_t)m*1024 + n];
      }
    }
  }
}

// ---------------- row LayerNorm: tmp fp32 [4096][1024] -> fp32 out ----------------
__global__ __launch_bounds__(256) void ln_kernel(const float* __restrict__ tmp, const float* __restrict__ g,
                                                 const float* __restrict__ b, float* __restrict__ out) {
  const int row = blockIdx.x;
  const int tid = threadIdx.x;
  const float* p = tmp + (size_t)row*D_;
  float4 v = *(const float4*)(p + tid*4);
  float s  = v.x + v.y + v.z + v.w;
  float sq = v.x*v.x + v.y*v.y + v.z*v.z + v.w*v.w;
  #pragma unroll
  for (int off=32; off>0; off>>=1) { s += __shfl_down(s, off); sq += __shfl_down(sq, off); }
  __shared__ float red[8];
  __shared__ float stats[2];
  const int wave = tid >> 6, lane = tid & 63;
  if (lane == 0) { red[wave] = s; red[4+wave] = sq; }
  __syncthreads();
  if (tid == 0) {
    float S = red[0]+red[1]+red[2]+red[3];
    float Q = red[4]+red[5]+red[6]+red[7];
    float mu = S * (1.0f/D_);
    float var = Q * (1.0f/D_) - mu*mu;
    stats[0] = mu;
    stats[1] = rsqrtf(var + 1e-5f);
  }
  __syncthreads();
  const float mu = stats[0], rstd = stats[1];
  const float vals[4] = {v.x, v.y, v.z, v.w};
  float4 o;
  float* op = (float*)&o;
  #pragma unroll
  for (int c=0;c<4;c++) op[c] = (vals[c]-mu)*rstd*g[tid*4+c] + b[tid*4+c];
  *(float4*)(out + (size_t)row*D_ + tid*4) = o;
}

extern "C" void kernel_launch(void* const* d_in, const int* in_sizes, int n_in,
                              void* d_out, int out_size, void* d_ws, size_t ws_size,
                              hipStream_t stream) {
  (void)in_sizes; (void)n_in; (void)out_size; (void)ws_size;
  const float* x  = (const float*)d_in[0];
  const float* Wq = (const float*)d_in[1];
  const float* bq = (const float*)d_in[2];
  const float* Wk = (const float*)d_in[3];
  const float* bk = (const float*)d_in[4];
  const float* Wv = (const float*)d_in[5];
  const float* bv = (const float*)d_in[6];
  const float* Wo = (const float*)d_in[7];
  const float* bo = (const float*)d_in[8];
  const float* lg = (const float*)d_in[9];
  const float* lb = (const float*)d_in[10];
  float* out = (float*)d_out;

  char* ws = (char*)d_ws;
  bf16* wt  = (bf16*)ws;  ws += (size_t)4*1024*1024*sizeof(bf16);   // Wq,Wk,Wv,Wo transposed, bf16 (8 MB)
  bf16* Xb  = (bf16*)ws;  ws += (size_t)M_*D_*sizeof(bf16);         // x cast to bf16 (8 MB)
  bf16* Vb  = (bf16*)ws;  ws += (size_t)M_*D_*sizeof(bf16);         // V  (8 MB)
  bf16* Ob  = (bf16*)ws;  ws += (size_t)M_*D_*sizeof(bf16);         // attn out (8 MB)
  bf16* Qb  = (bf16*)ws;  ws += (size_t)M_*D_*sizeof(bf16);         // Q  (8 MB)
  bf16* Kb  = (bf16*)ws;  ws += (size_t)M_*D_*sizeof(bf16);         // K  (8 MB)
  float* tmp = (float*)Qb;   // fp32 [4096][1024] overlays Q+K (dead after attention)

  cast_x<<<M_*D_/(256*8), 256, 0, stream>>>(x, Xb);
  transpose4<<<dim3(32,32,4), dim3(32,8), 0, stream>>>(Wq, Wk, Wv, Wo, wt);
  qkv_gemm<<<dim3(32,24), 256, 0, stream>>>(Xb, wt, bq, bk, bv, Qb, Kb, Vb);
  attn_kernel<<<dim3(T_/64, B_*H_), 256, 0, stream>>>(Qb, Kb, Vb, Ob);
  proj_gemm<<<dim3(32,8), 256, 0, stream>>>(Ob, wt + (size_t)3*1024*1024, bo, x, tmp);
  ln_kernel<<<M_, 256, 0, stream>>>(tmp, lg, lb, out);
}